// Round 2
// baseline (73.895 us; speedup 1.0000x reference)
//
#include <hip/hip_runtime.h>

#define B 512
#define D 256
#define NCLS 10
#define MARGIN 0.2f
#define THREADS 1024
#define NWAVES (THREADS / 64)   // 16 waves, 4/SIMD
#define ROWS 2
#define NBLOCKS (B / ROWS)      // 256 blocks = 1/CU
#define DT 32                   // D-slice per tile (floats)
#define NDT (D / DT)            // 8 tiles
#define TILE_FLOATS (B * DT)    // 16384 floats = 64 KB per buffer

// v3: kill the LDS-instruction bottleneck (v2: 160 LDS wave-ops/thread ~= 12.8us
// of LDS pipe) and the 16 full-drain __syncthreads.
//  - staging: global_load_lds dwordx4 (async, zero ds_write instrs), linear LDS
//    dest, XOR placement swizzle applied to the per-lane GLOBAL source
//    (both-sides-or-neither): LDS quad p holds global (j=p>>3, e4=(p&7)^s_j),
//    s_j=(j&7)^((j>>3)&7). Read of (j,e4) at quad 8j+(e4^s_j): per 8-lane
//    group quad%8 = e4^u^v all distinct -> conflict-free b128.
//  - anchors: block-uniform addresses -> scalar loads from global (K$),
//    SGPR operands in FMA; zero LDS broadcast reads.
//  - e-split: thread (j, h=t>>9) computes BOTH rows over e-half h: 32 x-reads
//    feed 256 FMAs; partials combined via one float2 LDS round trip.
//  - 2-phase pipeline: double buffer, counted s_waitcnt vmcnt(4), raw
//    s_barrier (no vmcnt(0) drain in-loop), sched_barrier(0) guards.
__global__ __launch_bounds__(THREADS) void fused_loss_kernel(
    const float* __restrict__ F, const int* __restrict__ labels,
    float* __restrict__ out)
{
    __shared__ float  buf[2][TILE_FLOATS];   // 128 KB
    __shared__ float2 part[2][B];            // 8 KB partial dots (.x=row0,.y=row1)
    __shared__ float  pos_vals[ROWS][B + 4]; // +4: float4 tail pad
    __shared__ float  neg_vals[ROWS][B];
    __shared__ int    lbl[B];
    __shared__ int    cnt[ROWS][2];
    __shared__ int    hist[NCLS];
    __shared__ float  wred[NWAVES];
    __shared__ int    vred[NWAVES];

    const int t    = threadIdx.x;
    const int lane = t & 63;
    const int w    = t >> 6;
    const int i0   = blockIdx.x * ROWS;
    const int h    = t >> 9;                 // wave-uniform e-half select
    const int j    = t & (B - 1);            // owned sim column
    const int sj   = (j & 7) ^ ((j >> 3) & 7);
    const int h4   = __builtin_amdgcn_readfirstlane(h << 2);  // e4 base {0,4}

    // async DMA stage of one tile: 4096 quads, 4 per thread; dest wave-uniform
    // base + lane*16 (linear); source pre-swizzled per lane.
    auto stage = [&](float* dstbase, int tile) {
#pragma unroll
        for (int k = 0; k < 4; ++k) {
            const int p  = (w << 8) + (k << 6) + lane;
            const int jj = p >> 3;
            const int e4 = (p & 7) ^ (jj & 7) ^ ((jj >> 3) & 7);
            const float* src = F + jj * D + tile * DT + (e4 << 2);
            float* dst = dstbase + (w << 10) + (k << 8);
            __builtin_amdgcn_global_load_lds(
                (const __attribute__((address_space(1))) void*)src,
                (__attribute__((address_space(3))) void*)dst, 16, 0, 0);
        }
    };

    // LDS init writes, then kick off tile-0 DMA before anything else
    if (t < B)        lbl[t] = labels[t];
    if (t < NCLS)     hist[t] = 0;
    if (t < ROWS * 2) ((int*)cnt)[t] = 0;
    stage(buf[0], 0);

    // barrier that drains LDS writes but NOT the tile-0 vmcnt
    asm volatile("s_waitcnt lgkmcnt(0)" ::: "memory");
    __builtin_amdgcn_s_barrier();

    if (t < B) atomicAdd(&hist[lbl[t]], 1);  // 10-bin LDS histogram

    // ---- sim phase: 2-phase pipelined tiles ----
    float acc0 = 0.f, acc1 = 0.f;
    const float* Fa0 = F + (size_t)i0 * D;   // block-uniform -> scalar loads
    const float* Fa1 = Fa0 + D;
    int cur = 0;
    for (int tile = 0; tile < NDT; ++tile) {
        if (tile + 1 < NDT) {
            stage(buf[cur ^ 1], tile + 1);               // prefetch next tile
            asm volatile("s_waitcnt vmcnt(4)" ::: "memory");  // this tile done
        } else {
            asm volatile("s_waitcnt vmcnt(0)" ::: "memory");
        }
        __builtin_amdgcn_s_barrier();        // all waves' DMA for cur landed
        __builtin_amdgcn_sched_barrier(0);
        const float* bufc = buf[cur];
        const int dt = tile * DT;
#pragma unroll
        for (int k = 0; k < 4; ++k) {
            const int e4 = h4 + k;
            const float4 x  = *(const float4*)&bufc[(j << 5) + ((e4 ^ sj) << 2)];
            const float4 a0 = *(const float4*)&Fa0[dt + (e4 << 2)];  // s_load
            const float4 a1 = *(const float4*)&Fa1[dt + (e4 << 2)];  // s_load
            acc0 = fmaf(a0.x, x.x, acc0); acc0 = fmaf(a0.y, x.y, acc0);
            acc0 = fmaf(a0.z, x.z, acc0); acc0 = fmaf(a0.w, x.w, acc0);
            acc1 = fmaf(a1.x, x.x, acc1); acc1 = fmaf(a1.y, x.y, acc1);
            acc1 = fmaf(a1.z, x.z, acc1); acc1 = fmaf(a1.w, x.w, acc1);
        }
        __builtin_amdgcn_sched_barrier(0);   // keep reads+FMAs before barrier
        __builtin_amdgcn_s_barrier();        // cur safe to overwrite next iter
        cur ^= 1;
    }

    // combine e-halves: sim[r][j] = part[0][j].r + part[1][j].r
    part[h][j] = make_float2(acc0, acc1);
    __syncthreads();
    const float2 pA = part[0][j];
    const float2 pB = part[1][j];
    const float  sv = h ? (pA.y + pB.y) : (pA.x + pB.x);

    // num_valid: row j valid iff 2 <= c[l_j] <= B-1 (counted once, by h=0 half)
    {
        bool valid = false;
        if (t < B) { const int c = hist[lbl[t]]; valid = (c >= 2) && (c <= B - 1); }
        const unsigned long long mv = __ballot(valid);
        if (lane == 0) vred[w] = __popcll(mv);
    }

    // ---- hinge phase: both rows concurrently (wave-half per row) ----
    const int r   = h;
    const int i_r = i0 + r;
    const int li  = lbl[i_r];
    {
        const bool active = (j != i_r);
        const bool ispos  = active && (lbl[j] == li);
        const bool isneg  = active && (lbl[j] != li);
        const unsigned long long mp = __ballot(ispos);
        const unsigned long long mn = __ballot(isneg);
        int basep = 0, basen = 0;
        if (lane == 0) {
            basep = atomicAdd(&cnt[r][0], __popcll(mp));
            basen = atomicAdd(&cnt[r][1], __popcll(mn));
        }
        basep = __shfl(basep, 0, 64);
        basen = __shfl(basen, 0, 64);
        const unsigned long long below = (1ull << lane) - 1ull;
        if (ispos) pos_vals[r][basep + __popcll(mp & below)] = sv;
        if (isneg) neg_vals[r][basen + __popcll(mn & below)] = sv;
    }
    __syncthreads();
    const int P = cnt[r][0], N = cnt[r][1];
    if (j < 4) pos_vals[r][P + j] = 1e30f;   // +INF pad -> relu clamps to 0
    __syncthreads();

    // thread owns one neg value; float4 pos reads (13 b128 vs 51 b32 per wave)
    const float nv_t = (j < N) ? neg_vals[r][j] : -1e30f;
    float local = 0.f;
    for (int pi = 0; pi < P; pi += 4) {
        const float4 pv = *(const float4*)&pos_vals[r][pi];
        float v;
        v = nv_t - (pv.x - MARGIN); local += (v > 0.f) ? v : 0.f;
        v = nv_t - (pv.y - MARGIN); local += (v > 0.f) ? v : 0.f;
        v = nv_t - (pv.z - MARGIN); local += (v > 0.f) ? v : 0.f;
        v = nv_t - (pv.w - MARGIN); local += (v > 0.f) ? v : 0.f;
    }

    // block reduction: wave64 shuffle, then across 16 waves via LDS
#pragma unroll
    for (int off = 32; off > 0; off >>= 1)
        local += __shfl_down(local, off, 64);
    if (lane == 0) wred[w] = local;
    __syncthreads();
    if (t == 0) {
        float s = 0.f;
        int   nv = 0;
#pragma unroll
        for (int k = 0; k < NWAVES; ++k) { s += wred[k]; nv += vred[k]; }
        const int   clast = hist[lbl[B - 1]];
        const float denom = (float)nv * (float)(clast - 1) * (float)(B - clast);
        atomicAdd(out, (denom > 0.f) ? s / denom : 0.f);
    }
}

extern "C" void kernel_launch(void* const* d_in, const int* in_sizes, int n_in,
                              void* d_out, int out_size, void* d_ws, size_t ws_size,
                              hipStream_t stream) {
    const float* F      = (const float*)d_in[0];   // [512, 256] fp32
    const int*   labels = (const int*)d_in[1];     // [512] int32
    float* out = (float*)d_out;
    (void)d_ws; (void)ws_size;

    fused_loss_kernel<<<NBLOCKS, THREADS, 0, stream>>>(F, labels, out);
}

// Round 3
// 67.378 us; speedup vs baseline: 1.0967x; 1.0967x over previous
//
#include <hip/hip_runtime.h>

#define B 512
#define D 256
#define NCLS 10
#define MARGIN 0.2f
#define THREADS 1024
#define NWAVES (THREADS / 64)   // 16 waves, 4/SIMD
#define ROWS 2
#define NBLOCKS (B / ROWS)      // 256 blocks = 1/CU
#define DT 32                   // D-slice per tile (floats)
#define NDT (D / DT)            // 8 tiles
#define TILE_FLOATS (B * DT)    // 16384 floats = 64 KB per buffer

// v4 = v3 with the vmcnt-entanglement regression fixed + fewer LDS ops.
//  - anchors staged ONCE into LDS fi[2][256] in the prologue; compute loop has
//    ZERO global VMEM -> s_waitcnt vmcnt(4) counts only the DMA prefetch, so
//    the double-buffer pipeline actually stays in flight (v3 bug: per-tile
//    anchor global loads forced vmcnt drains).
//  - micro-tile: thread (g=t>>2, q=t&3) computes cols {2g,2g+1} x rows {0,1}
//    over e-quarter q of each tile: per k-step 2 x-reads + 2 anchor-reads
//    feed 16 FMAs -> 64 b128 LDS reads/thread total (v2: 160, v3: 96+8 glb).
//    Partials combined 4-way via LDS aliased onto dead buf[0].
//  - staging unchanged from v3 (verified): global_load_lds dwordx4, linear LDS
//    dest, XOR placement swizzle on the per-lane GLOBAL source; read of
//    (j,e4) at quad 8j+(e4^sj), sj=(j&7)^((j>>3)&7).
//    Read conflict check per 8-lane group: j in {4a,4a+2}, e4=2q+k ->
//    quad%32 in blocks {0..7} + {16..23}, 4 distinct e4^sj each -> 8 distinct
//    banks, conflict-free.
__global__ __launch_bounds__(THREADS) void fused_loss_kernel(
    const float* __restrict__ F, const int* __restrict__ labels,
    float* __restrict__ out)
{
    __shared__ float  buf[2][TILE_FLOATS];   // 128 KB
    __shared__ float  fi[ROWS][D];           // anchor rows (2 KB)
    __shared__ float  pos_vals[ROWS][B + 4]; // +4: float4 tail pad
    __shared__ float  neg_vals[ROWS][B];
    __shared__ int    lbl[B];
    __shared__ int    cnt[ROWS][2];
    __shared__ int    hist[NCLS];
    __shared__ float  wred[NWAVES];
    __shared__ int    vred[NWAVES];

    const int t    = threadIdx.x;
    const int lane = t & 63;
    const int w    = t >> 6;
    const int i0   = blockIdx.x * ROWS;
    const int q    = t & 3;                  // e-quarter within tile
    const int g    = t >> 2;                 // col-pair index (0..255)
    const int j0   = 2 * g;
    const int j1   = 2 * g + 1;
    const int s0   = (j0 & 7) ^ ((j0 >> 3) & 7);
    const int s1   = (j1 & 7) ^ ((j1 >> 3) & 7);

    // async DMA stage of one tile: 4096 quads, 4 per thread; dest wave-uniform
    // base + lane*16 (linear); source pre-swizzled per lane.
    auto stage = [&](float* dstbase, int tile) {
#pragma unroll
        for (int k = 0; k < 4; ++k) {
            const int p  = (w << 8) + (k << 6) + lane;
            const int jj = p >> 3;
            const int e4 = (p & 7) ^ (jj & 7) ^ ((jj >> 3) & 7);
            const float* src = F + jj * D + tile * DT + (e4 << 2);
            float* dst = dstbase + (w << 10) + (k << 8);
            __builtin_amdgcn_global_load_lds(
                (const __attribute__((address_space(1))) void*)src,
                (__attribute__((address_space(3))) void*)dst, 16, 0, 0);
        }
    };

    // LDS init writes + anchor staging, then kick off tile-0 DMA
    if (t < B)        lbl[t] = labels[t];
    if (t < NCLS)     hist[t] = 0;
    if (t < ROWS * 2) ((int*)cnt)[t] = 0;
    if (t < (ROWS * D) / 4)
        ((float4*)fi)[t] = ((const float4*)(F + (size_t)i0 * D))[t];
    stage(buf[0], 0);

    // drain LDS writes (incl. fi's dependent vector loads) but not tile-0 DMA
    // beyond what the compiler needs for fi; one-time cost.
    asm volatile("s_waitcnt lgkmcnt(0)" ::: "memory");
    __builtin_amdgcn_s_barrier();

    if (t < B) atomicAdd(&hist[lbl[t]], 1);  // 10-bin LDS histogram

    // ---- sim phase: 2-phase pipelined tiles, zero global VMEM in loop ----
    float acc00 = 0.f, acc01 = 0.f, acc10 = 0.f, acc11 = 0.f; // acc[c][r]
    int cur = 0;
    for (int tile = 0; tile < NDT; ++tile) {
        if (tile + 1 < NDT) {
            stage(buf[cur ^ 1], tile + 1);               // prefetch next tile
            asm volatile("s_waitcnt vmcnt(4)" ::: "memory");  // this tile done
        } else {
            asm volatile("s_waitcnt vmcnt(0)" ::: "memory");
        }
        __builtin_amdgcn_s_barrier();        // all waves' DMA for cur landed
        __builtin_amdgcn_sched_barrier(0);
        const float* bufc = buf[cur];
        const int dt = tile * DT;
#pragma unroll
        for (int k = 0; k < 2; ++k) {
            const int e4 = 2 * q + k;
            const float4 x0 = *(const float4*)&bufc[(j0 << 5) + ((e4 ^ s0) << 2)];
            const float4 x1 = *(const float4*)&bufc[(j1 << 5) + ((e4 ^ s1) << 2)];
            const float4 a0 = *(const float4*)&fi[0][dt + (e4 << 2)];
            const float4 a1 = *(const float4*)&fi[1][dt + (e4 << 2)];
            acc00 = fmaf(a0.x, x0.x, acc00); acc00 = fmaf(a0.y, x0.y, acc00);
            acc00 = fmaf(a0.z, x0.z, acc00); acc00 = fmaf(a0.w, x0.w, acc00);
            acc01 = fmaf(a1.x, x0.x, acc01); acc01 = fmaf(a1.y, x0.y, acc01);
            acc01 = fmaf(a1.z, x0.z, acc01); acc01 = fmaf(a1.w, x0.w, acc01);
            acc10 = fmaf(a0.x, x1.x, acc10); acc10 = fmaf(a0.y, x1.y, acc10);
            acc10 = fmaf(a0.z, x1.z, acc10); acc10 = fmaf(a0.w, x1.w, acc10);
            acc11 = fmaf(a1.x, x1.x, acc11); acc11 = fmaf(a1.y, x1.y, acc11);
            acc11 = fmaf(a1.z, x1.z, acc11); acc11 = fmaf(a1.w, x1.w, acc11);
        }
        __builtin_amdgcn_sched_barrier(0);   // keep reads+FMAs before barrier
        __builtin_amdgcn_s_barrier();        // cur safe to overwrite next iter
        cur ^= 1;
    }

    // 4-way partial combine via LDS aliased onto dead buf[0] (tile 7 used
    // buf[1]; trailing barrier above guarantees no wave still reads buf[0]).
    float2* part = (float2*)buf[0];          // part[q*512 + j] = (row0, row1)
    part[(q << 9) + j0] = make_float2(acc00, acc01);
    part[(q << 9) + j1] = make_float2(acc10, acc11);
    __syncthreads();
    const int j = t & (B - 1);               // owned sim column
    const int h = t >> 9;                    // wave-uniform row select
    const float2 p0 = part[(0 << 9) + j];
    const float2 p1 = part[(1 << 9) + j];
    const float2 p2 = part[(2 << 9) + j];
    const float2 p3 = part[(3 << 9) + j];
    const float sv = h ? (p0.y + p1.y + p2.y + p3.y)
                       : (p0.x + p1.x + p2.x + p3.x);

    // num_valid: row j valid iff 2 <= c[l_j] <= B-1 (h=0 half counts)
    {
        bool valid = false;
        if (t < B) { const int c = hist[lbl[t]]; valid = (c >= 2) && (c <= B - 1); }
        const unsigned long long mv = __ballot(valid);
        if (lane == 0) vred[w] = __popcll(mv);
    }

    // ---- hinge phase: both rows concurrently (wave-half per row) ----
    const int r   = h;
    const int i_r = i0 + r;
    const int li  = lbl[i_r];
    {
        const bool active = (j != i_r);
        const bool ispos  = active && (lbl[j] == li);
        const bool isneg  = active && (lbl[j] != li);
        const unsigned long long mp = __ballot(ispos);
        const unsigned long long mn = __ballot(isneg);
        int basep = 0, basen = 0;
        if (lane == 0) {
            basep = atomicAdd(&cnt[r][0], __popcll(mp));
            basen = atomicAdd(&cnt[r][1], __popcll(mn));
        }
        basep = __shfl(basep, 0, 64);
        basen = __shfl(basen, 0, 64);
        const unsigned long long below = (1ull << lane) - 1ull;
        if (ispos) pos_vals[r][basep + __popcll(mp & below)] = sv;
        if (isneg) neg_vals[r][basen + __popcll(mn & below)] = sv;
    }
    __syncthreads();
    const int P = cnt[r][0], N = cnt[r][1];
    if (j < 4) pos_vals[r][P + j] = 1e30f;   // +INF pad -> relu clamps to 0
    __syncthreads();

    // thread owns one neg value; float4 pos reads (broadcast b128)
    const float nv_t = (j < N) ? neg_vals[r][j] : -1e30f;
    float local = 0.f;
    for (int pi = 0; pi < P; pi += 4) {
        const float4 pv = *(const float4*)&pos_vals[r][pi];
        float v;
        v = nv_t - (pv.x - MARGIN); local += (v > 0.f) ? v : 0.f;
        v = nv_t - (pv.y - MARGIN); local += (v > 0.f) ? v : 0.f;
        v = nv_t - (pv.z - MARGIN); local += (v > 0.f) ? v : 0.f;
        v = nv_t - (pv.w - MARGIN); local += (v > 0.f) ? v : 0.f;
    }

    // block reduction: wave64 shuffle, then across 16 waves via LDS
#pragma unroll
    for (int off = 32; off > 0; off >>= 1)
        local += __shfl_down(local, off, 64);
    if (lane == 0) wred[w] = local;
    __syncthreads();
    if (t == 0) {
        float s = 0.f;
        int   nv = 0;
#pragma unroll
        for (int k = 0; k < NWAVES; ++k) { s += wred[k]; nv += vred[k]; }
        const int   clast = hist[lbl[B - 1]];
        const float denom = (float)nv * (float)(clast - 1) * (float)(B - clast);
        atomicAdd(out, (denom > 0.f) ? s / denom : 0.f);
    }
}

extern "C" void kernel_launch(void* const* d_in, const int* in_sizes, int n_in,
                              void* d_out, int out_size, void* d_ws, size_t ws_size,
                              hipStream_t stream) {
    const float* F      = (const float*)d_in[0];   // [512, 256] fp32
    const int*   labels = (const int*)d_in[1];     // [512] int32
    float* out = (float*)d_out;
    (void)d_ws; (void)ws_size;

    fused_loss_kernel<<<NBLOCKS, THREADS, 0, stream>>>(F, labels, out);
}